// Round 10
// baseline (972.707 us; speedup 1.0000x reference)
//
#include <hip/hip_runtime.h>
#include <hip/hip_bf16.h>
#include <math.h>

#define NN 100000
#define NNP 100096          // padded to 1564*64
#define NE 300000
#define HID 128
#define EMB 64
#define NG 4096
#define DEG_CAP 32
#define XS 512              // X row stride in elements

typedef __bf16 bf16x8 __attribute__((ext_vector_type(8)));
typedef float  f32x16 __attribute__((ext_vector_type(16)));
typedef short  short8 __attribute__((ext_vector_type(8)));

typedef const __attribute__((address_space(1))) unsigned int* gas_u32;
typedef __attribute__((address_space(3))) unsigned int* las_u32;

__device__ __forceinline__ void gload16(const void* g, void* l) {
    __builtin_amdgcn_global_load_lds((gas_u32)g, (las_u32)l, 16, 0, 0);
}
__device__ __forceinline__ void gload16nt(const void* g, void* l) {
    // aux=2 (NT): streaming A-tile must not evict Bf from per-XCD L2
    __builtin_amdgcn_global_load_lds((gas_u32)g, (las_u32)l, 16, 0, 2);
}

__device__ __forceinline__ float bf2f(unsigned short u) {
    unsigned int x = ((unsigned int)u) << 16;
    return __builtin_bit_cast(float, x);
}
__device__ __forceinline__ unsigned short f2bf(float f) {
    unsigned int x = __builtin_bit_cast(unsigned int, f);
    unsigned int r = x + 0x7fff + ((x >> 16) & 1);
    return (unsigned short)(r >> 16);
}
__device__ __forceinline__ float sigm(float x) { return 1.f / (1.f + __expf(-x)); }

// ---------------------------------------------------------------------------
// h init: node_features f32 -> Y bf16 [NNP][128]; pad rows zeroed.
// (X h-window is populated by k_agg each step -> no cross-block write races.)
// ---------------------------------------------------------------------------
__global__ __launch_bounds__(256) void k_init(const float* __restrict__ nf,
                                              unsigned short* __restrict__ Y) {
    int id = blockIdx.x * 256 + threadIdx.x;   // NNP*HID
    int n = id >> 7, c = id & 127;
    Y[(long)n * HID + c] = (n < NN) ? f2bf(nf[(long)n * HID + c]) : (unsigned short)0;
}

// ---------------------------------------------------------------------------
// CSR build (deg true counts; csr capped at DEG_CAP)
// ---------------------------------------------------------------------------
__global__ __launch_bounds__(256) void k_build_csr(const int* __restrict__ ei,
                                                   int* __restrict__ deg,
                                                   int* __restrict__ csr) {
    int id = blockIdx.x * 256 + threadIdx.x;
    if (id >= 3 * NE) return;
    int t = id / NE;
    int i = id - t * NE;
    int src = ei[(t * 2 + 0) * NE + i];
    int dst = ei[(t * 2 + 1) * NE + i];
    int p = atomicAdd(&deg[t * NN + dst], 1);
    if (p < DEG_CAP) csr[((long)t * NN + dst) * DEG_CAP + p] = src;
}

__global__ __launch_bounds__(256) void k_pack_deg(const int* __restrict__ deg,
                                                  int4* __restrict__ degp) {
    int n = blockIdx.x * 256 + threadIdx.x;
    if (n >= NNP) return;
    int4 v; v.x = 0; v.y = 0; v.z = 0; v.w = 0;
    if (n < NN) { v.x = deg[n]; v.y = deg[NN + n]; v.z = deg[2 * NN + n]; }
    degp[n] = v;
}

// ---------------------------------------------------------------------------
// Bf: FRAGMENT-ORDERED weights. n' = c*4 + sec (sec-minor). For MFMA
// 32x32x16 B-operand, lane = kg*32 + nl supplies B[n' = nb*32+nl]
// [k = k16*16 + kg*8 + e]. Fragment (nb,k16) = contiguous 1KB.
// K layout: k<384 -> A_cat (Wm @ Wih_sec^T), k>=384 -> h (Whh_sec).
// ---------------------------------------------------------------------------
__global__ __launch_bounds__(512) void k_build_w(const float* __restrict__ Wmsg,
                                                 const float* __restrict__ Wih,
                                                 const float* __restrict__ Whh,
                                                 unsigned short* __restrict__ Bf) {
    int np = blockIdx.x;       // 0..511 permuted col
    int k = threadIdx.x;       // 0..511
    int c = np >> 2, sec = np & 3;
    float v = 0.f;
    if (k < 384) {
        if (sec < 3) {
            int t = k >> 7, kk = k & 127;
            const float* wm = Wmsg + ((long)t * HID + kk) * HID;
            const float* wi = Wih + (long)(sec * HID + c) * HID;
            float s = 0.f;
            for (int j = 0; j < HID; j++) s += wm[j] * wi[j];
            v = s;
        }
    } else {
        int kk = k - 384;
        if (sec == 0)      v = Whh[(long)c * HID + kk];
        else if (sec == 1) v = Whh[(long)(HID + c) * HID + kk];
        else if (sec == 3) v = Whh[(long)(2 * HID + c) * HID + kk];
    }
    int nb = np >> 5, nl = np & 31;
    int k16 = k >> 4, kgg = (k >> 3) & 1, e = k & 7;
    Bf[((((nb * 32 + k16) * 2 + kgg) * 32 + nl) << 3) + e] = f2bf(v);
}

__global__ __launch_bounds__(512) void k_build_bias(const float* __restrict__ bih,
                                                    const float* __restrict__ bhh,
                                                    const float* __restrict__ bmsg,
                                                    const float* __restrict__ Wih,
                                                    float* __restrict__ bbig,
                                                    float* __restrict__ Bdeg) {
    int np = threadIdx.x;      // 0..511 permuted
    int c = np >> 2, sec = np & 3;
    float b;
    if (sec == 0)      b = bih[c] + bhh[c];
    else if (sec == 1) b = bih[HID + c] + bhh[HID + c];
    else if (sec == 2) b = bih[2 * HID + c];
    else               b = bhh[2 * HID + c];
    bbig[np] = b;
    for (int t = 0; t < 3; t++) {
        float s = 0.f;
        if (sec < 3) {
            const float* wi = Wih + (long)(sec * HID + c) * HID;
            const float* bm = bmsg + t * HID;
            for (int j = 0; j < HID; j++) s += bm[j] * wi[j];
        }
        Bdeg[t * 512 + np] = s;
    }
}

// ---------------------------------------------------------------------------
// Aggregate: one WAVE per node, gather from compact Y [n][128], write A_cat
// into X cols 0..383 AND copy h (Y row) into X cols 384..511 (sequenced by
// the dispatch boundary -> gru never writes X, no cross-block races).
// ---------------------------------------------------------------------------
__global__ __launch_bounds__(256) void k_agg(const unsigned short* __restrict__ Y,
                                             unsigned short* __restrict__ X,
                                             const int* __restrict__ deg,
                                             const int* __restrict__ csr) {
    const int lane = threadIdx.x & 63;
    const long n = (long)blockIdx.x * 4 + (threadIdx.x >> 6);
    const int g = lane >> 4;
    const int c16 = lane & 15;
    const int l31 = lane & 31;

    int d[3], il[3];
#pragma unroll
    for (int t = 0; t < 3; t++) {
        int dt = deg[t * NN + n];
        d[t] = dt > DEG_CAP ? DEG_CAP : dt;
        il[t] = csr[((long)t * NN + n) * DEG_CAP + l31];
    }
#pragma unroll
    for (int t = 0; t < 3; t++) {
        float acc[8] = {0.f, 0.f, 0.f, 0.f, 0.f, 0.f, 0.f, 0.f};
        int rounds = (d[t] + 3) >> 2;
        for (int r = 0; r < rounds; r++) {
            int j = r * 4 + g;
            int idx = __shfl(il[t], j & 31);
            if (j < d[t]) {
                short8 v = *(const short8*)(Y + (long)idx * HID + c16 * 8);
#pragma unroll
                for (int q = 0; q < 8; q++) acc[q] += bf2f((unsigned short)v[q]);
            }
        }
#pragma unroll
        for (int q = 0; q < 8; q++) {
            acc[q] += __shfl_xor(acc[q], 16);
            acc[q] += __shfl_xor(acc[q], 32);
        }
        if (g == 0) {
            short8 o;
#pragma unroll
            for (int q = 0; q < 8; q++) o[q] = (short)f2bf(acc[q]);
            *(short8*)(X + n * XS + t * HID + c16 * 8) = o;
        }
    }
    if (g == 1) {   // h copy: Y row -> X cols 384..511
        short8 v = *(const short8*)(Y + n * HID + c16 * 8);
        *(short8*)(X + n * XS + 384 + c16 * 8) = v;
    }
}

// ---------------------------------------------------------------------------
// Fused GRU step: [A_cat|h] (K=512) x Bf (N=512) + gates.
// BM=64, BN=256 (grid 2 x 1564), 8 waves, wave tile 64x32 (2x1 of 32x32):
// acc = 32 AGPR -> room for DEPTH-4 explicit B prefetch (rotating static
// slots) within 128 unified regs -> 4 waves/SIMD, 2 blocks/CU (LDS 64KB).
// A staged ONCE for all K (64 frags x 1KB, NT DMA so the A-stream doesn't
// evict Bf from per-XCD L2); K-loop is barrier-free, conflict-free b128.
// Writes h ONLY to Y (X h-window is k_agg's job -> no races).
// Epilogue: 4 bands x 16 rows through 16KB EX (reused LDS).
// ---------------------------------------------------------------------------
__global__ __launch_bounds__(512, 4) void k_gru_mfma(
        const unsigned short* __restrict__ X,
        const unsigned short* __restrict__ Y,
        unsigned short* __restrict__ Yw,
        const unsigned short* __restrict__ Bf,
        const float* __restrict__ bbig, const float* __restrict__ Bdeg,
        const int4* __restrict__ degp) {
    __shared__ char lds[65536];     // A: 64 frags x 1KB; low 16KB reused as EX

    const int tid = threadIdx.x;
    const int lane = tid & 63;
    const int wv = tid >> 6;        // 0..7 = N slot (32 cols each)
    const int r31 = lane & 31;
    const int kg = lane >> 5;
    const int bnN = blockIdx.x;     // 0..1 N half
    const long row0 = (long)blockIdx.y * 64;

    f32x16 acc0 = (f32x16)(0.0f);   // rows 0..31
    f32x16 acc1 = (f32x16)(0.0f);   // rows 32..63

    // A staging (whole K at once): frag f = k16*2 + mt; wave wv stages
    // f = wv*8 + jj. lane -> row mt*32 + r31, byte col k16*32 + kg*16.
    {
        const char* base = (const char*)X + (row0 + r31) * 1024 + kg * 16;
#pragma unroll
        for (int jj = 0; jj < 8; jj++) {
            const int f = wv * 8 + jj;
            gload16nt(base + (f & 1) * 32768 + (f >> 1) * 32, lds + f * 1024);
        }
    }

    // B: wave owns global nb = bnN*8 + wv (cols nb*32..+31), fragment-ordered.
    const unsigned short* pB = Bf + (long)(bnN * 8 + wv) * 16384 + lane * 8;

    // depth-4 prefetch slots (static rotation after full unroll)
    short8 bs0 = *(const short8*)(pB);
    short8 bs1 = *(const short8*)(pB + 512);
    short8 bs2 = *(const short8*)(pB + 1024);
    short8 bs3 = *(const short8*)(pB + 1536);

    __syncthreads();                // drains vmcnt(0): A tile + B slots ready

#pragma unroll
    for (int it = 0; it < 32; it++) {
        short8 a0 = *(const short8*)(lds + (it * 2 + 0) * 1024 + lane * 16);
        short8 a1 = *(const short8*)(lds + (it * 2 + 1) * 1024 + lane * 16);
        short8 b;
        if ((it & 3) == 0) b = bs0;
        else if ((it & 3) == 1) b = bs1;
        else if ((it & 3) == 2) b = bs2;
        else b = bs3;
        if (it + 4 < 32) {
            const short8 nb = *(const short8*)(pB + (it + 4) * 512);
            if ((it & 3) == 0) bs0 = nb;
            else if ((it & 3) == 1) bs1 = nb;
            else if ((it & 3) == 2) bs2 = nb;
            else bs3 = nb;
        }
        acc0 = __builtin_amdgcn_mfma_f32_32x32x16_bf16(
            __builtin_bit_cast(bf16x8, a0), __builtin_bit_cast(bf16x8, b), acc0, 0, 0, 0);
        acc1 = __builtin_amdgcn_mfma_f32_32x32x16_bf16(
            __builtin_bit_cast(bf16x8, a1), __builtin_bit_cast(bf16x8, b), acc1, 0, 0, 0);
    }

    // ---- epilogue: 4 bands of 16 rows; EX = [16][256] f32 = 16KB ----
    float* EX = (float*)lds;
    const int ch = lane;                    // local channel 0..63
    const int gch = bnN * 64 + ch;          // global channel 0..127
    const float4 bb = *(const float4*)(bbig + bnN * 256 + ch * 4);
    const float4 e0 = *(const float4*)(Bdeg + bnN * 256 + ch * 4);
    const float4 e1 = *(const float4*)(Bdeg + 512 + bnN * 256 + ch * 4);
    const float4 e2 = *(const float4*)(Bdeg + 1024 + bnN * 256 + ch * 4);

#pragma unroll
    for (int b = 0; b < 4; b++) {
        __syncthreads();
        {
            const int qh = (b & 1) * 8;
            const int col = wv * 32 + r31;
#pragma unroll
            for (int qq = 0; qq < 8; qq++) {
                int rwl = (qq & 3) + 8 * (qq >> 2) + 4 * kg;   // 0..15
                EX[rwl * 256 + col] = (b >> 1) ? acc1[qh + qq] : acc0[qh + qq];
            }
        }
        __syncthreads();
#pragma unroll
        for (int i = 0; i < 2; i++) {
            int rwl = wv + 8 * i;           // 0..15
            long grow = row0 + b * 16 + rwl;
            int4 dg = degp[grow];
            float dgx = (float)dg.x, dgy = (float)dg.y, dgz = (float)dg.z;
            float4 v = *(const float4*)(EX + rwl * 256 + ch * 4);
            float Sr = v.x + bb.x + dgx * e0.x + dgy * e1.x + dgz * e2.x;
            float Sz = v.y + bb.y + dgx * e0.y + dgy * e1.y + dgz * e2.y;
            float In = v.z + bb.z + dgx * e0.z + dgy * e1.z + dgz * e2.z;
            float Hn = v.w + bb.w;          // sec3 deg-bias is 0 by construction
            float rr = sigm(Sr);
            float zz = sigm(Sz);
            float tt = In + rr * Hn;
            float ee = __expf(2.f * tt);
            float nn = 1.f - 2.f / (ee + 1.f);
            float hv = (1.f - zz) * nn + zz * bf2f(Y[grow * HID + gch]);
            Yw[grow * HID + gch] = f2bf(hv);
        }
    }
}

// ---------------------------------------------------------------------------
// Readout: out[g] += sigmoid(h@Wg.T+bg) * (h@Wp.T+bp). h from Y bf16.
// ---------------------------------------------------------------------------
__global__ __launch_bounds__(256) void k_readout(const unsigned short* __restrict__ Y,
                                                 const int* __restrict__ n2g,
                                                 const float* __restrict__ Wp,
                                                 const float* __restrict__ bp,
                                                 const float* __restrict__ Wg,
                                                 const float* __restrict__ bg,
                                                 float* __restrict__ out) {
    __shared__ float hs[32][132];
    __shared__ float Ws[64][129];
    int tid = threadIdx.x;
    long row0 = (long)blockIdx.x * 32;
    int rg = tid >> 5, cg = tid & 31;
    float acc[4][4];
#pragma unroll
    for (int r = 0; r < 4; r++)
#pragma unroll
        for (int c = 0; c < 4; c++) acc[r][c] = 0.f;

#pragma unroll
    for (int p = 0; p < 2; p++) {
        int e = p * 256 + tid;
        int r = e >> 4, c8 = e & 15;
        short8 v = *(const short8*)(Y + (row0 + r) * HID + c8 * 8);
#pragma unroll
        for (int j = 0; j < 8; j++) hs[r][c8 * 8 + j] = bf2f((unsigned short)v[j]);
    }
    for (int kc = 0; kc < 128; kc += 64) {
        __syncthreads();
#pragma unroll
        for (int p = 0; p < 8; p++) {
            int idx = p * 256 + tid;
            int j = idx >> 4, q = idx & 15;
            const float* Wsrc = (j < 64) ? Wp : Wg;
            float4 w = *(const float4*)&Wsrc[(j & 63) * HID + kc + q * 4];
            Ws[q * 4 + 0][j] = w.x;
            Ws[q * 4 + 1][j] = w.y;
            Ws[q * 4 + 2][j] = w.z;
            Ws[q * 4 + 3][j] = w.w;
        }
        __syncthreads();
#pragma unroll 8
        for (int k = 0; k < 64; k++) {
            float a[4], w[4];
#pragma unroll
            for (int r = 0; r < 4; r++) a[r] = hs[rg * 4 + r][kc + k];
#pragma unroll
            for (int c = 0; c < 4; c++) w[c] = Ws[k][cg + 32 * c];
#pragma unroll
            for (int r = 0; r < 4; r++)
#pragma unroll
                for (int c = 0; c < 4; c++) acc[r][c] += a[r] * w[c];
        }
    }
#pragma unroll
    for (int r = 0; r < 4; r++) {
        long row = row0 + rg * 4 + r;
        if (row < NN) {
            int g = n2g[row];
            float pv0 = acc[r][0] + bp[cg];
            float pv1 = acc[r][1] + bp[cg + 32];
            float gv0 = acc[r][2] + bg[cg];
            float gv1 = acc[r][3] + bg[cg + 32];
            atomicAdd(&out[g * EMB + cg],      pv0 * sigm(gv0));
            atomicAdd(&out[g * EMB + cg + 32], pv1 * sigm(gv1));
        }
    }
}

// ---------------------------------------------------------------------------
extern "C" void kernel_launch(void* const* d_in, const int* in_sizes, int n_in,
                              void* d_out, int out_size, void* d_ws, size_t ws_size,
                              hipStream_t stream) {
    const float* node_features = (const float*)d_in[0];
    const int*   edge_index    = (const int*)d_in[1];
    const int*   n2g           = (const int*)d_in[2];
    const float* W_msg         = (const float*)d_in[3];
    const float* b_msg         = (const float*)d_in[4];
    const float* W_ih          = (const float*)d_in[5];
    const float* W_hh          = (const float*)d_in[6];
    const float* b_ih          = (const float*)d_in[7];
    const float* b_hh          = (const float*)d_in[8];
    const float* W_proj        = (const float*)d_in[9];
    const float* b_proj        = (const float*)d_in[10];
    const float* W_gate        = (const float*)d_in[11];
    const float* b_gate        = (const float*)d_in[12];

    char* ws = (char*)d_ws;
    unsigned short* X    = (unsigned short*)(ws);                 // 102,498,304 B
    unsigned short* Y    = (unsigned short*)(ws + 102498304);     //  25,624,576 B
    unsigned short* Bf   = (unsigned short*)(ws + 128122880);     //     524,288 B
    float*          bbig = (float*)         (ws + 128647168);     //       2,048 B
    float*          Bdeg = (float*)         (ws + 128649216);     //       6,144 B
    int4*           degp = (int4*)          (ws + 128655360);     //   1,601,536 B
    int*            deg  = (int*)           (ws + 130256896);     //   1,200,000 B
    int*            csr  = (int*)           (ws + 131456896);     //  38,400,000 B -> 169,856,896

    float* out = (float*)d_out;

    hipMemsetAsync(out, 0, (size_t)NG * EMB * sizeof(float), stream);
    hipMemsetAsync(deg, 0, (size_t)3 * NN * sizeof(int), stream);

    k_init<<<dim3((NNP * HID) / 256), dim3(256), 0, stream>>>(node_features, Y);
    k_build_csr<<<dim3((3 * NE + 255) / 256), dim3(256), 0, stream>>>(edge_index, deg, csr);
    k_pack_deg<<<dim3(NNP / 256), dim3(256), 0, stream>>>(deg, degp);
    k_build_w<<<dim3(512), dim3(512), 0, stream>>>(W_msg, W_ih, W_hh, Bf);
    k_build_bias<<<dim3(1), dim3(512), 0, stream>>>(b_ih, b_hh, b_msg, W_ih, bbig, Bdeg);

    for (int step = 0; step < 4; step++) {
        k_agg<<<dim3(NN / 4), dim3(256), 0, stream>>>(Y, X, deg, csr);
        k_gru_mfma<<<dim3(2, NNP / 64), dim3(512), 0, stream>>>(X, Y, Y, Bf,
                                                                bbig, Bdeg, degp);
    }
    k_readout<<<dim3(NN / 32), dim3(256), 0, stream>>>(Y, n2g, W_proj, b_proj,
                                                       W_gate, b_gate, out);
}

// Round 11
// 970.016 us; speedup vs baseline: 1.0028x; 1.0028x over previous
//
#include <hip/hip_runtime.h>
#include <hip/hip_bf16.h>
#include <math.h>

#define NN 100000
#define NNP 100096          // padded to 1564*64
#define NE 300000
#define HID 128
#define EMB 64
#define NG 4096
#define DEG_CAP 32
#define XS 512              // X row stride in elements

typedef __bf16 bf16x8 __attribute__((ext_vector_type(8)));
typedef float  f32x16 __attribute__((ext_vector_type(16)));
typedef short  short8 __attribute__((ext_vector_type(8)));

typedef const __attribute__((address_space(1))) unsigned int* gas_u32;
typedef __attribute__((address_space(3))) unsigned int* las_u32;

__device__ __forceinline__ void gload16(const void* g, void* l) {
    __builtin_amdgcn_global_load_lds((gas_u32)g, (las_u32)l, 16, 0, 0);
}

__device__ __forceinline__ float bf2f(unsigned short u) {
    unsigned int x = ((unsigned int)u) << 16;
    return __builtin_bit_cast(float, x);
}
__device__ __forceinline__ unsigned short f2bf(float f) {
    unsigned int x = __builtin_bit_cast(unsigned int, f);
    unsigned int r = x + 0x7fff + ((x >> 16) & 1);
    return (unsigned short)(r >> 16);
}
__device__ __forceinline__ float sigm(float x) { return 1.f / (1.f + __expf(-x)); }

#define MFMA(A, B, C) __builtin_amdgcn_mfma_f32_32x32x16_bf16( \
    __builtin_bit_cast(bf16x8, A), __builtin_bit_cast(bf16x8, B), C, 0, 0, 0)

// ---------------------------------------------------------------------------
// h init: node_features f32 -> Y bf16 [NNP][128]; pad rows zeroed.
// ---------------------------------------------------------------------------
__global__ __launch_bounds__(256) void k_init(const float* __restrict__ nf,
                                              unsigned short* __restrict__ Y) {
    int id = blockIdx.x * 256 + threadIdx.x;   // NNP*HID
    int n = id >> 7, c = id & 127;
    Y[(long)n * HID + c] = (n < NN) ? f2bf(nf[(long)n * HID + c]) : (unsigned short)0;
}

// ---------------------------------------------------------------------------
// CSR build (deg true counts; csr capped at DEG_CAP)
// ---------------------------------------------------------------------------
__global__ __launch_bounds__(256) void k_build_csr(const int* __restrict__ ei,
                                                   int* __restrict__ deg,
                                                   int* __restrict__ csr) {
    int id = blockIdx.x * 256 + threadIdx.x;
    if (id >= 3 * NE) return;
    int t = id / NE;
    int i = id - t * NE;
    int src = ei[(t * 2 + 0) * NE + i];
    int dst = ei[(t * 2 + 1) * NE + i];
    int p = atomicAdd(&deg[t * NN + dst], 1);
    if (p < DEG_CAP) csr[((long)t * NN + dst) * DEG_CAP + p] = src;
}

__global__ __launch_bounds__(256) void k_pack_deg(const int* __restrict__ deg,
                                                  int4* __restrict__ degp) {
    int n = blockIdx.x * 256 + threadIdx.x;
    if (n >= NNP) return;
    int4 v; v.x = 0; v.y = 0; v.z = 0; v.w = 0;
    if (n < NN) { v.x = deg[n]; v.y = deg[NN + n]; v.z = deg[2 * NN + n]; }
    degp[n] = v;
}

// ---------------------------------------------------------------------------
// Bf: FRAGMENT-ORDERED weights. n' = c*4 + sec (sec-minor). For MFMA
// 32x32x16 B-operand, lane = kg*32 + nl supplies B[n' = nb*32+nl]
// [k = k16*16 + kg*8 + e]. Fragment (nb,k16) = contiguous 1KB.
// K layout: k<384 -> A_cat (Wm @ Wih_sec^T), k>=384 -> h (Whh_sec).
// ---------------------------------------------------------------------------
__global__ __launch_bounds__(512) void k_build_w(const float* __restrict__ Wmsg,
                                                 const float* __restrict__ Wih,
                                                 const float* __restrict__ Whh,
                                                 unsigned short* __restrict__ Bf) {
    int np = blockIdx.x;       // 0..511 permuted col
    int k = threadIdx.x;       // 0..511
    int c = np >> 2, sec = np & 3;
    float v = 0.f;
    if (k < 384) {
        if (sec < 3) {
            int t = k >> 7, kk = k & 127;
            const float* wm = Wmsg + ((long)t * HID + kk) * HID;
            const float* wi = Wih + (long)(sec * HID + c) * HID;
            float s = 0.f;
            for (int j = 0; j < HID; j++) s += wm[j] * wi[j];
            v = s;
        }
    } else {
        int kk = k - 384;
        if (sec == 0)      v = Whh[(long)c * HID + kk];
        else if (sec == 1) v = Whh[(long)(HID + c) * HID + kk];
        else if (sec == 3) v = Whh[(long)(2 * HID + c) * HID + kk];
    }
    int nb = np >> 5, nl = np & 31;
    int k16 = k >> 4, kgg = (k >> 3) & 1, e = k & 7;
    Bf[((((nb * 32 + k16) * 2 + kgg) * 32 + nl) << 3) + e] = f2bf(v);
}

__global__ __launch_bounds__(512) void k_build_bias(const float* __restrict__ bih,
                                                    const float* __restrict__ bhh,
                                                    const float* __restrict__ bmsg,
                                                    const float* __restrict__ Wih,
                                                    float* __restrict__ bbig,
                                                    float* __restrict__ Bdeg) {
    int np = threadIdx.x;      // 0..511 permuted
    int c = np >> 2, sec = np & 3;
    float b;
    if (sec == 0)      b = bih[c] + bhh[c];
    else if (sec == 1) b = bih[HID + c] + bhh[HID + c];
    else if (sec == 2) b = bih[2 * HID + c];
    else               b = bhh[2 * HID + c];
    bbig[np] = b;
    for (int t = 0; t < 3; t++) {
        float s = 0.f;
        if (sec < 3) {
            const float* wi = Wih + (long)(sec * HID + c) * HID;
            const float* bm = bmsg + t * HID;
            for (int j = 0; j < HID; j++) s += bm[j] * wi[j];
        }
        Bdeg[t * 512 + np] = s;
    }
}

// ---------------------------------------------------------------------------
// Aggregate: one WAVE per node, gather from compact Y [n][128], write A_cat
// into X cols 0..383 AND copy h (Y row) into X cols 384..511.
// ---------------------------------------------------------------------------
__global__ __launch_bounds__(256) void k_agg(const unsigned short* __restrict__ Y,
                                             unsigned short* __restrict__ X,
                                             const int* __restrict__ deg,
                                             const int* __restrict__ csr) {
    const int lane = threadIdx.x & 63;
    const long n = (long)blockIdx.x * 4 + (threadIdx.x >> 6);
    const int g = lane >> 4;
    const int c16 = lane & 15;
    const int l31 = lane & 31;

    int d[3], il[3];
#pragma unroll
    for (int t = 0; t < 3; t++) {
        int dt = deg[t * NN + n];
        d[t] = dt > DEG_CAP ? DEG_CAP : dt;
        il[t] = csr[((long)t * NN + n) * DEG_CAP + l31];
    }
#pragma unroll
    for (int t = 0; t < 3; t++) {
        float acc[8] = {0.f, 0.f, 0.f, 0.f, 0.f, 0.f, 0.f, 0.f};
        int rounds = (d[t] + 3) >> 2;
        for (int r = 0; r < rounds; r++) {
            int j = r * 4 + g;
            int idx = __shfl(il[t], j & 31);
            if (j < d[t]) {
                short8 v = *(const short8*)(Y + (long)idx * HID + c16 * 8);
#pragma unroll
                for (int q = 0; q < 8; q++) acc[q] += bf2f((unsigned short)v[q]);
            }
        }
#pragma unroll
        for (int q = 0; q < 8; q++) {
            acc[q] += __shfl_xor(acc[q], 16);
            acc[q] += __shfl_xor(acc[q], 32);
        }
        if (g == 0) {
            short8 o;
#pragma unroll
            for (int q = 0; q < 8; q++) o[q] = (short)f2bf(acc[q]);
            *(short8*)(X + n * XS + t * HID + c16 * 8) = o;
        }
    }
    if (g == 1) {   // h copy: Y row -> X cols 384..511
        short8 v = *(const short8*)(Y + n * HID + c16 * 8);
        *(short8*)(X + n * XS + 384 + c16 * 8) = v;
    }
}

// ---------------------------------------------------------------------------
// Fused GRU step: [A_cat|h] (K=512) x Bf (N=512) + gates.
// BM=64, BN=512, 4 waves, wave tile 64x128 (2x4 of 32x32): acc = 128 AGPR,
// MFMA:ds_read ratio = 4 (the cross-round scaling law: MfmaUtil ~ 10% x ratio;
// R8's ratio-2 hit 18%). B from L2 with DEPTH-2 software pipeline (even/odd
// rotating slots, issued one full k16-pair ahead) -> latency covered at
// 2 waves/SIMD. A staged ONCE for all K (64KB LDS, DMA, no NT); loop is
// barrier-free, ds_read conflict-free. Writes h ONLY to Y (no races).
// Epilogue: 8 bands x 8 rows through 16KB EX (reused LDS).
// ---------------------------------------------------------------------------
__global__ __launch_bounds__(256, 2) void k_gru_mfma(
        const unsigned short* __restrict__ X,
        const unsigned short* __restrict__ Y,
        unsigned short* __restrict__ Yw,
        const unsigned short* __restrict__ Bf,
        const float* __restrict__ bbig, const float* __restrict__ Bdeg,
        const int4* __restrict__ degp) {
    __shared__ char lds[65536];     // A: 64 frags x 1KB; low 16KB reused as EX

    const int tid = threadIdx.x;
    const int lane = tid & 63;
    const int wv = tid >> 6;        // 0..3, owns cols wv*128..+127
    const int r31 = lane & 31;
    const int kg = lane >> 5;
    const long row0 = (long)blockIdx.x * 64;

    f32x16 acc[2][4];
#pragma unroll
    for (int i = 0; i < 2; i++)
#pragma unroll
        for (int j = 0; j < 4; j++) acc[i][j] = (f32x16)(0.0f);

    // A staging (whole K): frag f = k16*2 + mt at lds[f*1024 + lane*16];
    // lane kg*32+r31 holds A[row0 + mt*32 + r31][k16*16 + kg*8 .. +8].
    {
        const char* base = (const char*)X + (row0 + r31) * 1024 + kg * 16;
#pragma unroll
        for (int jj = 0; jj < 16; jj++) {
            const int f = wv * 16 + jj;
            gload16(base + (f & 1) * 32768 + (f >> 1) * 32, lds + f * 1024);
        }
    }

    // B fragment pointers: wave owns nb = wv*4 + j (cols wv*128 + j*32 ..+31)
    const unsigned short* pB0 = Bf + (long)(wv * 4 + 0) * 16384 + lane * 8;
    const unsigned short* pB1 = Bf + (long)(wv * 4 + 1) * 16384 + lane * 8;
    const unsigned short* pB2 = Bf + (long)(wv * 4 + 2) * 16384 + lane * 8;
    const unsigned short* pB3 = Bf + (long)(wv * 4 + 3) * 16384 + lane * 8;

    // depth-2 pipeline: even slots (k16 = 2it), odd slots (k16 = 2it+1)
    short8 e0 = *(const short8*)(pB0);
    short8 e1 = *(const short8*)(pB1);
    short8 e2 = *(const short8*)(pB2);
    short8 e3 = *(const short8*)(pB3);
    short8 o0 = *(const short8*)(pB0 + 512);
    short8 o1 = *(const short8*)(pB1 + 512);
    short8 o2 = *(const short8*)(pB2 + 512);
    short8 o3 = *(const short8*)(pB3 + 512);

    __syncthreads();                // A tile ready

#pragma unroll
    for (int it = 0; it < 16; it++) {
        const int k16 = it * 2;
        {   // even k16
            short8 a0 = *(const short8*)(lds + (k16 * 2 + 0) * 1024 + lane * 16);
            short8 a1 = *(const short8*)(lds + (k16 * 2 + 1) * 1024 + lane * 16);
            acc[0][0] = MFMA(a0, e0, acc[0][0]);
            acc[0][1] = MFMA(a0, e1, acc[0][1]);
            acc[0][2] = MFMA(a0, e2, acc[0][2]);
            acc[0][3] = MFMA(a0, e3, acc[0][3]);
            acc[1][0] = MFMA(a1, e0, acc[1][0]);
            acc[1][1] = MFMA(a1, e1, acc[1][1]);
            acc[1][2] = MFMA(a1, e2, acc[1][2]);
            acc[1][3] = MFMA(a1, e3, acc[1][3]);
            if (it < 15) {
                e0 = *(const short8*)(pB0 + (k16 + 2) * 512);
                e1 = *(const short8*)(pB1 + (k16 + 2) * 512);
                e2 = *(const short8*)(pB2 + (k16 + 2) * 512);
                e3 = *(const short8*)(pB3 + (k16 + 2) * 512);
            }
        }
        {   // odd k16+1
            short8 a0 = *(const short8*)(lds + ((k16 + 1) * 2 + 0) * 1024 + lane * 16);
            short8 a1 = *(const short8*)(lds + ((k16 + 1) * 2 + 1) * 1024 + lane * 16);
            acc[0][0] = MFMA(a0, o0, acc[0][0]);
            acc[0][1] = MFMA(a0, o1, acc[0][1]);
            acc[0][2] = MFMA(a0, o2, acc[0][2]);
            acc[0][3] = MFMA(a0, o3, acc[0][3]);
            acc[1][0] = MFMA(a1, o0, acc[1][0]);
            acc[1][1] = MFMA(a1, o1, acc[1][1]);
            acc[1][2] = MFMA(a1, o2, acc[1][2]);
            acc[1][3] = MFMA(a1, o3, acc[1][3]);
            if (it < 15) {
                o0 = *(const short8*)(pB0 + (k16 + 3) * 512);
                o1 = *(const short8*)(pB1 + (k16 + 3) * 512);
                o2 = *(const short8*)(pB2 + (k16 + 3) * 512);
                o3 = *(const short8*)(pB3 + (k16 + 3) * 512);
            }
        }
    }

    // ---- epilogue: 8 bands of 8 rows; EX = [8][512] f32 = 16KB ----
    float* EX = (float*)lds;
#pragma unroll
    for (int b = 0; b < 8; b++) {
        __syncthreads();
        {
            const int mt = b >> 2;          // which 32-row fragment
            const int q1 = b & 3;           // acc-reg quartet
#pragma unroll
            for (int ct = 0; ct < 4; ct++) {
                int col = wv * 128 + ct * 32 + r31;
#pragma unroll
                for (int q0 = 0; q0 < 4; q0++) {
                    int rb = 4 * kg + q0;   // row within band, 0..7
                    EX[rb * 512 + col] = acc[mt][ct][q1 * 4 + q0];
                }
            }
        }
        __syncthreads();
        {
            const int row = tid >> 5;       // 0..7
            long grow = row0 + b * 8 + row;
            int4 dg = degp[grow];
            float dgx = (float)dg.x, dgy = (float)dg.y, dgz = (float)dg.z;
#pragma unroll
            for (int i = 0; i < 4; i++) {
                int ch = (tid & 31) + 32 * i;    // channel 0..127
                float4 v  = *(const float4*)(EX + row * 512 + ch * 4);
                float4 bb = *(const float4*)(bbig + ch * 4);
                float4 q0 = *(const float4*)(Bdeg + ch * 4);
                float4 q1 = *(const float4*)(Bdeg + 512 + ch * 4);
                float4 q2 = *(const float4*)(Bdeg + 1024 + ch * 4);
                float Sr = v.x + bb.x + dgx * q0.x + dgy * q1.x + dgz * q2.x;
                float Sz = v.y + bb.y + dgx * q0.y + dgy * q1.y + dgz * q2.y;
                float In = v.z + bb.z + dgx * q0.z + dgy * q1.z + dgz * q2.z;
                float Hn = v.w + bb.w;      // sec3 deg-bias is 0 by construction
                float rr = sigm(Sr);
                float zz = sigm(Sz);
                float tt = In + rr * Hn;
                float ee = __expf(2.f * tt);
                float nn = 1.f - 2.f / (ee + 1.f);
                float hv = (1.f - zz) * nn + zz * bf2f(Y[grow * HID + ch]);
                Yw[grow * HID + ch] = f2bf(hv);
            }
        }
    }
}

// ---------------------------------------------------------------------------
// Readout: out[g] += sigmoid(h@Wg.T+bg) * (h@Wp.T+bp). h from Y bf16.
// ---------------------------------------------------------------------------
__global__ __launch_bounds__(256) void k_readout(const unsigned short* __restrict__ Y,
                                                 const int* __restrict__ n2g,
                                                 const float* __restrict__ Wp,
                                                 const float* __restrict__ bp,
                                                 const float* __restrict__ Wg,
                                                 const float* __restrict__ bg,
                                                 float* __restrict__ out) {
    __shared__ float hs[32][132];
    __shared__ float Ws[64][129];
    int tid = threadIdx.x;
    long row0 = (long)blockIdx.x * 32;
    int rg = tid >> 5, cg = tid & 31;
    float acc[4][4];
#pragma unroll
    for (int r = 0; r < 4; r++)
#pragma unroll
        for (int c = 0; c < 4; c++) acc[r][c] = 0.f;

#pragma unroll
    for (int p = 0; p < 2; p++) {
        int e = p * 256 + tid;
        int r = e >> 4, c8 = e & 15;
        short8 v = *(const short8*)(Y + (row0 + r) * HID + c8 * 8);
#pragma unroll
        for (int j = 0; j < 8; j++) hs[r][c8 * 8 + j] = bf2f((unsigned short)v[j]);
    }
    for (int kc = 0; kc < 128; kc += 64) {
        __syncthreads();
#pragma unroll
        for (int p = 0; p < 8; p++) {
            int idx = p * 256 + tid;
            int j = idx >> 4, q = idx & 15;
            const float* Wsrc = (j < 64) ? Wp : Wg;
            float4 w = *(const float4*)&Wsrc[(j & 63) * HID + kc + q * 4];
            Ws[q * 4 + 0][j] = w.x;
            Ws[q * 4 + 1][j] = w.y;
            Ws[q * 4 + 2][j] = w.z;
            Ws[q * 4 + 3][j] = w.w;
        }
        __syncthreads();
#pragma unroll 8
        for (int k = 0; k < 64; k++) {
            float a[4], w[4];
#pragma unroll
            for (int r = 0; r < 4; r++) a[r] = hs[rg * 4 + r][kc + k];
#pragma unroll
            for (int c = 0; c < 4; c++) w[c] = Ws[k][cg + 32 * c];
#pragma unroll
            for (int r = 0; r < 4; r++)
#pragma unroll
                for (int c = 0; c < 4; c++) acc[r][c] += a[r] * w[c];
        }
    }
#pragma unroll
    for (int r = 0; r < 4; r++) {
        long row = row0 + rg * 4 + r;
        if (row < NN) {
            int g = n2g[row];
            float pv0 = acc[r][0] + bp[cg];
            float pv1 = acc[r][1] + bp[cg + 32];
            float gv0 = acc[r][2] + bg[cg];
            float gv1 = acc[r][3] + bg[cg + 32];
            atomicAdd(&out[g * EMB + cg],      pv0 * sigm(gv0));
            atomicAdd(&out[g * EMB + cg + 32], pv1 * sigm(gv1));
        }
    }
}

// ---------------------------------------------------------------------------
extern "C" void kernel_launch(void* const* d_in, const int* in_sizes, int n_in,
                              void* d_out, int out_size, void* d_ws, size_t ws_size,
                              hipStream_t stream) {
    const float* node_features = (const float*)d_in[0];
    const int*   edge_index    = (const int*)d_in[1];
    const int*   n2g           = (const int*)d_in[2];
    const float* W_msg         = (const float*)d_in[3];
    const float* b_msg         = (const float*)d_in[4];
    const float* W_ih          = (const float*)d_in[5];
    const float* W_hh          = (const float*)d_in[6];
    const float* b_ih          = (const float*)d_in[7];
    const float* b_hh          = (const float*)d_in[8];
    const float* W_proj        = (const float*)d_in[9];
    const float* b_proj        = (const float*)d_in[10];
    const float* W_gate        = (const float*)d_in[11];
    const float* b_gate        = (const float*)d_in[12];

    char* ws = (char*)d_ws;
    unsigned short* X    = (unsigned short*)(ws);                 // 102,498,304 B
    unsigned short* Y    = (unsigned short*)(ws + 102498304);     //  25,624,576 B
    unsigned short* Bf   = (unsigned short*)(ws + 128122880);     //     524,288 B
    float*          bbig = (float*)         (ws + 128647168);     //       2,048 B
    float*          Bdeg = (float*)         (ws + 128649216);     //       6,144 B
    int4*           degp = (int4*)          (ws + 128655360);     //   1,601,536 B
    int*            deg  = (int*)           (ws + 130256896);     //   1,200,000 B
    int*            csr  = (int*)           (ws + 131456896);     //  38,400,000 B -> 169,856,896

    float* out = (float*)d_out;

    hipMemsetAsync(out, 0, (size_t)NG * EMB * sizeof(float), stream);
    hipMemsetAsync(deg, 0, (size_t)3 * NN * sizeof(int), stream);

    k_init<<<dim3((NNP * HID) / 256), dim3(256), 0, stream>>>(node_features, Y);
    k_build_csr<<<dim3((3 * NE + 255) / 256), dim3(256), 0, stream>>>(edge_index, deg, csr);
    k_pack_deg<<<dim3(NNP / 256), dim3(256), 0, stream>>>(deg, degp);
    k_build_w<<<dim3(512), dim3(512), 0, stream>>>(W_msg, W_ih, W_hh, Bf);
    k_build_bias<<<dim3(1), dim3(512), 0, stream>>>(b_ih, b_hh, b_msg, W_ih, bbig, Bdeg);

    for (int step = 0; step < 4; step++) {
        k_agg<<<dim3(NN / 4), dim3(256), 0, stream>>>(Y, X, deg, csr);
        k_gru_mfma<<<dim3(NNP / 64), dim3(256), 0, stream>>>(X, Y, Y, Bf,
                                                             bbig, Bdeg, degp);
    }
    k_readout<<<dim3(NN / 32), dim3(256), 0, stream>>>(Y, n2g, W_proj, b_proj,
                                                       W_gate, b_gate, out);
}

// Round 12
// 853.986 us; speedup vs baseline: 1.1390x; 1.1359x over previous
//
#include <hip/hip_runtime.h>
#include <hip/hip_bf16.h>
#include <math.h>

#define NN 100000
#define NNP 100096          // padded to 1564*64
#define NE 300000
#define HID 128
#define EMB 64
#define NG 4096
#define DEG_CAP 32
#define XS 512              // X row stride in elements

typedef __bf16 bf16x8 __attribute__((ext_vector_type(8)));
typedef float  f32x16 __attribute__((ext_vector_type(16)));
typedef short  short8 __attribute__((ext_vector_type(8)));

typedef const __attribute__((address_space(1))) unsigned int* gas_u32;
typedef __attribute__((address_space(3))) unsigned int* las_u32;

__device__ __forceinline__ void gload16(const void* g, void* l) {
    __builtin_amdgcn_global_load_lds((gas_u32)g, (las_u32)l, 16, 0, 0);
}

__device__ __forceinline__ float bf2f(unsigned short u) {
    unsigned int x = ((unsigned int)u) << 16;
    return __builtin_bit_cast(float, x);
}
__device__ __forceinline__ unsigned short f2bf(float f) {
    unsigned int x = __builtin_bit_cast(unsigned int, f);
    unsigned int r = x + 0x7fff + ((x >> 16) & 1);
    return (unsigned short)(r >> 16);
}
__device__ __forceinline__ float sigm(float x) { return 1.f / (1.f + __expf(-x)); }

#define MFMA(A, B, C) __builtin_amdgcn_mfma_f32_32x32x16_bf16( \
    __builtin_bit_cast(bf16x8, A), __builtin_bit_cast(bf16x8, B), C, 0, 0, 0)

// ---------------------------------------------------------------------------
// h init: node_features f32 -> Y bf16 [NNP][128]; pad rows zeroed.
// ---------------------------------------------------------------------------
__global__ __launch_bounds__(256) void k_init(const float* __restrict__ nf,
                                              unsigned short* __restrict__ Y) {
    int id = blockIdx.x * 256 + threadIdx.x;   // NNP*HID
    int n = id >> 7, c = id & 127;
    Y[(long)n * HID + c] = (n < NN) ? f2bf(nf[(long)n * HID + c]) : (unsigned short)0;
}

// ---------------------------------------------------------------------------
// CSR build (deg true counts; csr capped at DEG_CAP)
// ---------------------------------------------------------------------------
__global__ __launch_bounds__(256) void k_build_csr(const int* __restrict__ ei,
                                                   int* __restrict__ deg,
                                                   int* __restrict__ csr) {
    int id = blockIdx.x * 256 + threadIdx.x;
    if (id >= 3 * NE) return;
    int t = id / NE;
    int i = id - t * NE;
    int src = ei[(t * 2 + 0) * NE + i];
    int dst = ei[(t * 2 + 1) * NE + i];
    int p = atomicAdd(&deg[t * NN + dst], 1);
    if (p < DEG_CAP) csr[((long)t * NN + dst) * DEG_CAP + p] = src;
}

__global__ __launch_bounds__(256) void k_pack_deg(const int* __restrict__ deg,
                                                  int4* __restrict__ degp) {
    int n = blockIdx.x * 256 + threadIdx.x;
    if (n >= NNP) return;
    int4 v; v.x = 0; v.y = 0; v.z = 0; v.w = 0;
    if (n < NN) { v.x = deg[n]; v.y = deg[NN + n]; v.z = deg[2 * NN + n]; }
    degp[n] = v;
}

// ---------------------------------------------------------------------------
// Bf: FRAGMENT-ORDERED weights. n' = c*4 + sec (sec-minor). For MFMA
// 32x32x16 B-operand, lane = kg*32 + nl supplies B[n' = nb*32+nl]
// [k = k16*16 + kg*8 + e]. Fragment (nb,k16) = contiguous 1KB.
// K layout: k<384 -> A_cat (Wm @ Wih_sec^T), k>=384 -> h (Whh_sec).
// ---------------------------------------------------------------------------
__global__ __launch_bounds__(512) void k_build_w(const float* __restrict__ Wmsg,
                                                 const float* __restrict__ Wih,
                                                 const float* __restrict__ Whh,
                                                 unsigned short* __restrict__ Bf) {
    int np = blockIdx.x;       // 0..511 permuted col
    int k = threadIdx.x;       // 0..511
    int c = np >> 2, sec = np & 3;
    float v = 0.f;
    if (k < 384) {
        if (sec < 3) {
            int t = k >> 7, kk = k & 127;
            const float* wm = Wmsg + ((long)t * HID + kk) * HID;
            const float* wi = Wih + (long)(sec * HID + c) * HID;
            float s = 0.f;
            for (int j = 0; j < HID; j++) s += wm[j] * wi[j];
            v = s;
        }
    } else {
        int kk = k - 384;
        if (sec == 0)      v = Whh[(long)c * HID + kk];
        else if (sec == 1) v = Whh[(long)(HID + c) * HID + kk];
        else if (sec == 3) v = Whh[(long)(2 * HID + c) * HID + kk];
    }
    int nb = np >> 5, nl = np & 31;
    int k16 = k >> 4, kgg = (k >> 3) & 1, e = k & 7;
    Bf[((((nb * 32 + k16) * 2 + kgg) * 32 + nl) << 3) + e] = f2bf(v);
}

__global__ __launch_bounds__(512) void k_build_bias(const float* __restrict__ bih,
                                                    const float* __restrict__ bhh,
                                                    const float* __restrict__ bmsg,
                                                    const float* __restrict__ Wih,
                                                    float* __restrict__ bbig,
                                                    float* __restrict__ Bdeg) {
    int np = threadIdx.x;      // 0..511 permuted
    int c = np >> 2, sec = np & 3;
    float b;
    if (sec == 0)      b = bih[c] + bhh[c];
    else if (sec == 1) b = bih[HID + c] + bhh[HID + c];
    else if (sec == 2) b = bih[2 * HID + c];
    else               b = bhh[2 * HID + c];
    bbig[np] = b;
    for (int t = 0; t < 3; t++) {
        float s = 0.f;
        if (sec < 3) {
            const float* wi = Wih + (long)(sec * HID + c) * HID;
            const float* bm = bmsg + t * HID;
            for (int j = 0; j < HID; j++) s += bm[j] * wi[j];
        }
        Bdeg[t * 512 + np] = s;
    }
}

// ---------------------------------------------------------------------------
// Aggregate: one WAVE per node, gather from compact Y [n][128], write A_cat
// into X cols 0..383 AND copy h (Y row) into X cols 384..511.
// ---------------------------------------------------------------------------
__global__ __launch_bounds__(256) void k_agg(const unsigned short* __restrict__ Y,
                                             unsigned short* __restrict__ X,
                                             const int* __restrict__ deg,
                                             const int* __restrict__ csr) {
    const int lane = threadIdx.x & 63;
    const long n = (long)blockIdx.x * 4 + (threadIdx.x >> 6);
    const int g = lane >> 4;
    const int c16 = lane & 15;
    const int l31 = lane & 31;

    int d[3], il[3];
#pragma unroll
    for (int t = 0; t < 3; t++) {
        int dt = deg[t * NN + n];
        d[t] = dt > DEG_CAP ? DEG_CAP : dt;
        il[t] = csr[((long)t * NN + n) * DEG_CAP + l31];
    }
#pragma unroll
    for (int t = 0; t < 3; t++) {
        float acc[8] = {0.f, 0.f, 0.f, 0.f, 0.f, 0.f, 0.f, 0.f};
        int rounds = (d[t] + 3) >> 2;
        for (int r = 0; r < rounds; r++) {
            int j = r * 4 + g;
            int idx = __shfl(il[t], j & 31);
            if (j < d[t]) {
                short8 v = *(const short8*)(Y + (long)idx * HID + c16 * 8);
#pragma unroll
                for (int q = 0; q < 8; q++) acc[q] += bf2f((unsigned short)v[q]);
            }
        }
#pragma unroll
        for (int q = 0; q < 8; q++) {
            acc[q] += __shfl_xor(acc[q], 16);
            acc[q] += __shfl_xor(acc[q], 32);
        }
        if (g == 0) {
            short8 o;
#pragma unroll
            for (int q = 0; q < 8; q++) o[q] = (short)f2bf(acc[q]);
            *(short8*)(X + n * XS + t * HID + c16 * 8) = o;
        }
    }
    if (g == 1) {   // h copy: Y row -> X cols 384..511
        short8 v = *(const short8*)(Y + n * HID + c16 * 8);
        *(short8*)(X + n * XS + 384 + c16 * 8) = v;
    }
}

// ---------------------------------------------------------------------------
// Fused GRU step: [A_cat|h] (K=512) x Bf (N=512) + gates.
// K-loop = R8's proven structure VERBATIM (best measured: 120us, 0 conflicts,
// 68MB FETCH): BM=64, BN=512, 8 waves x (64x64 tile, acc[2][2]=64 AGPR),
// A staged per 256-K half via DMA (32KB), B from L2 fragment-ordered.
// EPILOGUE v2 (this round's single change — ablation of the epilogue cost):
// 2 halves x {barrier; row-major f32 EX[32][516] scatter (64 b32, 2-way-free);
// barrier; 8 items/thread: ONE ds_read_b128 = all 4 gate sections (sec-minor
// N-perm makes secs consecutive f32) + gate math + coalesced Y row-write}.
// 8->4 barriers, 128->64 LDS writes, 32->16 LDS reads, f32-exact (bit-identical
// output vs R8). Writes h ONLY to Y (race-free plumbing from R10).
// ---------------------------------------------------------------------------
__global__ __launch_bounds__(512, 4) void k_gru_mfma(
        const unsigned short* __restrict__ X,
        const unsigned short* __restrict__ Y,
        unsigned short* __restrict__ Yw,
        const unsigned short* __restrict__ Bf,
        const float* __restrict__ bbig, const float* __restrict__ Bdeg,
        const int4* __restrict__ degp) {
    __shared__ char lds[66048];     // A half-tile 32KB (K-loop); EX [32][516] f32 (epilogue)

    const int tid = threadIdx.x;
    const int lane = tid & 63;
    const int wv = tid >> 6;        // 0..7 = N slot (64 cols each)
    const int r31 = lane & 31;
    const int kg = lane >> 5;
    const long row0 = (long)blockIdx.x * 64;

    f32x16 acc[2][2];               // [mt (32-row half)][ct (32-col half)]
#pragma unroll
    for (int i = 0; i < 2; i++)
#pragma unroll
        for (int j = 0; j < 2; j++) acc[i][j] = (f32x16)(0.0f);

    // A staging: frag f = k16l*2 + mt; LDS[f*1024 + lane*16] holds
    // A[row = mt*32 + (l&31)][k = k16*16 + (l>>5)*8 ..+8]. Per half: 32 frags,
    // wave wv stages f = wv*4 + jj (jj 0..3). Global src is per-lane scatter.
    const char* pAl = (const char*)X + (row0 + r31) * 1024 + kg * 16;
#define STAGE_A(HALF)                                                           \
    {                                                                           \
        _Pragma("unroll")                                                       \
        for (int jj = 0; jj < 4; jj++) {                                        \
            const int f = wv * 4 + jj;                                          \
            gload16(pAl + (f & 1) * 32768 + ((HALF) * 16 + (f >> 1)) * 32,      \
                    lds + f * 1024);                                            \
        }                                                                       \
    }

    // B fragment base pointers (ushort units), coalesced 16B/lane.
    // Wave wv owns nb = wv*2, wv*2+1 (cols wv*64 .. wv*64+63).
    const unsigned short* pB0 = Bf + (wv * 2 + 0) * 16384 + lane * 8;
    const unsigned short* pB1 = Bf + (wv * 2 + 1) * 16384 + lane * 8;

    STAGE_A(0);
    __syncthreads();

#pragma unroll
    for (int k16l = 0; k16l < 16; k16l++) {
        short8 a0 = *(const short8*)(lds + (k16l * 2 + 0) * 1024 + lane * 16);
        short8 a1 = *(const short8*)(lds + (k16l * 2 + 1) * 1024 + lane * 16);
        short8 b0 = *(const short8*)(pB0 + k16l * 512);
        short8 b1 = *(const short8*)(pB1 + k16l * 512);
        acc[0][0] = MFMA(a0, b0, acc[0][0]);
        acc[0][1] = MFMA(a0, b1, acc[0][1]);
        acc[1][0] = MFMA(a1, b0, acc[1][0]);
        acc[1][1] = MFMA(a1, b1, acc[1][1]);
    }

    __syncthreads();
    STAGE_A(1);
    __syncthreads();

#pragma unroll
    for (int k16l = 0; k16l < 16; k16l++) {
        const int k16g = 16 + k16l;
        short8 a0 = *(const short8*)(lds + (k16l * 2 + 0) * 1024 + lane * 16);
        short8 a1 = *(const short8*)(lds + (k16l * 2 + 1) * 1024 + lane * 16);
        short8 b0 = *(const short8*)(pB0 + k16g * 512);
        short8 b1 = *(const short8*)(pB1 + k16g * 512);
        acc[0][0] = MFMA(a0, b0, acc[0][0]);
        acc[0][1] = MFMA(a0, b1, acc[0][1]);
        acc[1][0] = MFMA(a1, b0, acc[1][0]);
        acc[1][1] = MFMA(a1, b1, acc[1][1]);
    }

    // ---- epilogue v2: 2 halves; EX = [32 rows][516] f32 (16B-aligned rows) ----
    float* EX = (float*)lds;
    const int ch = tid & 127;               // channel 0..127
    const int r5b = tid >> 7;               // 0..3
    const float4 bb = *(const float4*)(bbig + ch * 4);
    const float4 q0v = *(const float4*)(Bdeg + ch * 4);
    const float4 q1v = *(const float4*)(Bdeg + 512 + ch * 4);
    const float4 q2v = *(const float4*)(Bdeg + 1024 + ch * 4);

#pragma unroll
    for (int half = 0; half < 2; half++) {
        __syncthreads();
        // scatter: lane's 16 acc values per ct -> EX[r5][col] (2-way-free banks)
#pragma unroll
        for (int ct = 0; ct < 2; ct++) {
            const int col = wv * 64 + ct * 32 + r31;
#pragma unroll
            for (int reg = 0; reg < 16; reg++) {
                int r5 = (reg & 3) + 8 * (reg >> 2) + 4 * kg;
                EX[r5 * 516 + col] = half ? acc[1][ct][reg] : acc[0][ct][reg];
            }
        }
        __syncthreads();
        // gather + gates: one b128 read = 4 gate sections of (row, ch)
#pragma unroll
        for (int i = 0; i < 8; i++) {
            const int r5 = r5b + 4 * i;     // 0..31
            long grow = row0 + half * 32 + r5;
            int4 dg = degp[grow];
            float dgx = (float)dg.x, dgy = (float)dg.y, dgz = (float)dg.z;
            float4 v = *(const float4*)(EX + r5 * 516 + ch * 4);
            float Sr = v.x + bb.x + dgx * q0v.x + dgy * q1v.x + dgz * q2v.x;
            float Sz = v.y + bb.y + dgx * q0v.y + dgy * q1v.y + dgz * q2v.y;
            float In = v.z + bb.z + dgx * q0v.z + dgy * q1v.z + dgz * q2v.z;
            float Hn = v.w + bb.w;          // sec3 deg-bias is 0 by construction
            float rr = sigm(Sr);
            float zz = sigm(Sz);
            float tt = In + rr * Hn;
            float ee = __expf(2.f * tt);
            float nn = 1.f - 2.f / (ee + 1.f);
            float hv = (1.f - zz) * nn + zz * bf2f(Y[grow * HID + ch]);
            Yw[grow * HID + ch] = f2bf(hv);
        }
    }
}

// ---------------------------------------------------------------------------
// Readout: out[g] += sigmoid(h@Wg.T+bg) * (h@Wp.T+bp). h from Y bf16.
// ---------------------------------------------------------------------------
__global__ __launch_bounds__(256) void k_readout(const unsigned short* __restrict__ Y,
                                                 const int* __restrict__ n2g,
                                                 const float* __restrict__ Wp,
                                                 const float* __restrict__ bp,
                                                 const float* __restrict__ Wg,
                                                 const float* __restrict__ bg,
                                                 float* __restrict__ out) {
    __shared__ float hs[32][132];
    __shared__ float Ws[64][129];
    int tid = threadIdx.x;
    long row0 = (long)blockIdx.x * 32;
    int rg = tid >> 5, cg = tid & 31;
    float acc[4][4];
#pragma unroll
    for (int r = 0; r < 4; r++)
#pragma unroll
        for (int c = 0; c < 4; c++) acc[r][c] = 0.f;

#pragma unroll
    for (int p = 0; p < 2; p++) {
        int e = p * 256 + tid;
        int r = e >> 4, c8 = e & 15;
        short8 v = *(const short8*)(Y + (row0 + r) * HID + c8 * 8);
#pragma unroll
        for (int j = 0; j < 8; j++) hs[r][c8 * 8 + j] = bf2f((unsigned short)v[j]);
    }
    for (int kc = 0; kc < 128; kc += 64) {
        __syncthreads();
#pragma unroll
        for (int p = 0; p < 8; p++) {
            int idx = p * 256 + tid;
            int j = idx >> 4, q = idx & 15;
            const float* Wsrc = (j < 64) ? Wp : Wg;
            float4 w = *(const float4*)&Wsrc[(j & 63) * HID + kc + q * 4];
            Ws[q * 4 + 0][j] = w.x;
            Ws[q * 4 + 1][j] = w.y;
            Ws[q * 4 + 2][j] = w.z;
            Ws[q * 4 + 3][j] = w.w;
        }
        __syncthreads();
#pragma unroll 8
        for (int k = 0; k < 64; k++) {
            float a[4], w[4];
#pragma unroll
            for (int r = 0; r < 4; r++) a[r] = hs[rg * 4 + r][kc + k];
#pragma unroll
            for (int c = 0; c < 4; c++) w[c] = Ws[k][cg + 32 * c];
#pragma unroll
            for (int r = 0; r < 4; r++)
#pragma unroll
                for (int c = 0; c < 4; c++) acc[r][c] += a[r] * w[c];
        }
    }
#pragma unroll
    for (int r = 0; r < 4; r++) {
        long row = row0 + rg * 4 + r;
        if (row < NN) {
            int g = n2g[row];
            float pv0 = acc[r][0] + bp[cg];
            float pv1 = acc[r][1] + bp[cg + 32];
            float gv0 = acc[r][2] + bg[cg];
            float gv1 = acc[r][3] + bg[cg + 32];
            atomicAdd(&out[g * EMB + cg],      pv0 * sigm(gv0));
            atomicAdd(&out[g * EMB + cg + 32], pv1 * sigm(gv1));
        }
    }
}

// ---------------------------------------------------------------------------
extern "C" void kernel_launch(void* const* d_in, const int* in_sizes, int n_in,
                              void* d_out, int out_size, void* d_ws, size_t ws_size,
                              hipStream_t stream) {
    const float* node_features = (const float*)d_in[0];
    const int*   edge_index    = (const int*)d_in[1];
    const int*   n2g           = (const int*)d_in[2];
    const float* W_msg         = (const float*)d_in[3];
    const float* b_msg         = (const float*)d_in[4];
    const float* W_ih          = (const float*)d_in[5];
    const float* W_hh          = (const float*)d_in[6];
    const float* b_ih          = (const float*)d_in[7];
    const float* b_hh          = (const float*)d_in[8];
    const float* W_proj        = (const float*)d_in[9];
    const float* b_proj        = (const float*)d_in[10];
    const float* W_gate        = (const float*)d_in[11];
    const float* b_gate        = (const float*)d_in[12];

    char* ws = (char*)d_ws;
    unsigned short* X    = (unsigned short*)(ws);                 // 102,498,304 B
    unsigned short* Y    = (unsigned short*)(ws + 102498304);     //  25,624,576 B
    unsigned short* Bf   = (unsigned short*)(ws + 128122880);     //     524,288 B
    float*          bbig = (float*)         (ws + 128647168);     //       2,048 B
    float*          Bdeg = (float*)         (ws + 128649216);     //       6,144 B
    int4*           degp = (int4*)          (ws + 128655360);     //   1,601,536 B
    int*            deg  = (int*)           (ws + 130256896);     //   1,200,000 B
    int*            csr  = (int*)           (ws + 131456896);     //  38,400,000 B -> 169,856,896

    float* out = (float*)d_out;

    hipMemsetAsync(out, 0, (size_t)NG * EMB * sizeof(float), stream);
    hipMemsetAsync(deg, 0, (size_t)3 * NN * sizeof(int), stream);

    k_init<<<dim3((NNP * HID) / 256), dim3(256), 0, stream>>>(node_features, Y);
    k_build_csr<<<dim3((3 * NE + 255) / 256), dim3(256), 0, stream>>>(edge_index, deg, csr);
    k_pack_deg<<<dim3(NNP / 256), dim3(256), 0, stream>>>(deg, degp);
    k_build_w<<<dim3(512), dim3(512), 0, stream>>>(W_msg, W_ih, W_hh, Bf);
    k_build_bias<<<dim3(1), dim3(512), 0, stream>>>(b_ih, b_hh, b_msg, W_ih, bbig, Bdeg);

    for (int step = 0; step < 4; step++) {
        k_agg<<<dim3(NN / 4), dim3(256), 0, stream>>>(Y, X, deg, csr);
        k_gru_mfma<<<dim3(NNP / 64), dim3(512), 0, stream>>>(X, Y, Y, Bf,
                                                             bbig, Bdeg, degp);
    }
    k_readout<<<dim3(NN / 32), dim3(256), 0, stream>>>(Y, n2g, W_proj, b_proj,
                                                       W_gate, b_gate, out);
}